// Round 3
// baseline (343.936 us; speedup 1.0000x reference)
//
#include <hip/hip_runtime.h>
#include <hip/hip_bf16.h>

typedef __attribute__((ext_vector_type(4))) float v4f;
typedef __attribute__((ext_vector_type(8))) short v8s;
typedef __attribute__((ext_vector_type(4))) unsigned v4u;
typedef __attribute__((ext_vector_type(2))) unsigned v2u;

// full RNE fp32->bf16 (prep kernel only)
__device__ __forceinline__ short f2bf(float f) {
  union { float f; unsigned u; } v; v.f = f;
  unsigned r = v.u + 0x7FFFu + ((v.u >> 16) & 1u);
  return (short)(r >> 16);
}
// packed 2xfp32 -> bf16x2, single v_cvt_pk_bf16_f32
__device__ __forceinline__ unsigned pk2(float a, float b) {
  union { __hip_bfloat162 h; unsigned u; } c;
  c.h = __float22bfloat162_rn(make_float2(a, b));
  return c.u;
}
// bf16x2 dword -> two f32
__device__ __forceinline__ float bflo(unsigned u) {
  union { float f; unsigned u; } v; v.u = u << 16; return v.f;
}
__device__ __forceinline__ float bfhi(unsigned u) {
  union { float f; unsigned u; } v; v.u = u & 0xFFFF0000u; return v.f;
}

// Pack W1 [128x256] and W2 [256x256] (row-major [k][n], fp32) into bf16 MFMA
// A-operand fragment order for the transposed product (W^T as A):
//   lane l of fragment (mt, kt) holds A'[n = mt*16 + (l&15)][k = kt*32 + (l>>4)*8 + j]
__global__ void pack_weights(const float* __restrict__ W1, const float* __restrict__ W2,
                             short* __restrict__ pW1, short* __restrict__ pW2) {
  int tid = blockIdx.x * 256 + threadIdx.x;
  if (tid < 32768) {
    int j = tid & 7, l = (tid >> 3) & 63, frag = tid >> 9;
    int mt = frag >> 2, kt = frag & 3;
    int n = mt * 16 + (l & 15);
    int k = kt * 32 + ((l >> 4) * 8) + j;
    pW1[tid] = f2bf(W1[k * 256 + n]);
  } else if (tid < 98304) {
    int t2 = tid - 32768;
    int j = t2 & 7, l = (t2 >> 3) & 63, frag = t2 >> 9;
    int mt = frag >> 3, kt = frag & 7;
    int n = mt * 16 + (l & 15);
    int k = kt * 32 + ((l >> 4) * 8) + j;
    pW2[t2] = f2bf(W2[k * 256 + n]);
  }
}

// ===================== node-table precompute =====================
// HuT[node][256] bf16 = xu @ W1a + b1   (b1 folded here, once)
// HmT[node][256] f32  = xm @ W1b        (f32: zero extra rounding)
// 256 threads = 4 waves; wave w owns out rows w*64..w*64+63 (mi=4).
// B-operand loaded straight from global (rows are consecutive nodes).
__global__ __launch_bounds__(256) void make_h(
    const float* __restrict__ xu, const float* __restrict__ xm,
    const short* __restrict__ pW1, const float* __restrict__ b1,
    short* __restrict__ HuT, float* __restrict__ HmT,
    int Nu, int Nm, int NU64)
{
  const int t = threadIdx.x;
  const int w = t >> 6, lane = t & 63, quad = lane >> 4, lp = lane & 15;
  const bool isU = (int)blockIdx.x < NU64;
  const int tile0 = isU ? (int)blockIdx.x : (int)blockIdx.x - NU64;
  const int N = isU ? Nu : Nm;
  const float* X = isU ? xu : xm;

  const v8s* w1v = (const v8s*)pW1;
  v8s rK[4][2];                      // user: kt 0..1 ; movie: kt 2..3 (k-offset 64)
#pragma unroll
  for (int mi = 0; mi < 4; ++mi)
#pragma unroll
    for (int kt = 0; kt < 2; ++kt)
      rK[mi][kt] = w1v[(((w * 4 + mi) * 4) + (isU ? kt : kt + 2)) * 64 + lane];
  v4f rbb[4];
#pragma unroll
  for (int mi = 0; mi < 4; ++mi)
    rbb[mi] = *(const v4f*)(b1 + w * 64 + mi * 16 + quad * 4);

  v4f acc[4][4];
#pragma unroll
  for (int mi = 0; mi < 4; ++mi)
#pragma unroll
    for (int ni = 0; ni < 4; ++ni)
      acc[mi][ni] = v4f{0.f, 0.f, 0.f, 0.f};

#pragma unroll
  for (int kt = 0; kt < 2; ++kt) {
    v8s bf[4];
#pragma unroll
    for (int ni = 0; ni < 4; ++ni) {
      int node = tile0 * 64 + ni * 16 + lp;
      if (node >= N) node = N - 1;
      const float* s = X + (size_t)node * 64 + kt * 32 + quad * 8;
      v4f x0 = *(const v4f*)s, x1 = *(const v4f*)(s + 4);
      union { v4u u; v8s s; } c;
      c.u = v4u{ pk2(x0[0], x0[1]), pk2(x0[2], x0[3]),
                 pk2(x1[0], x1[1]), pk2(x1[2], x1[3]) };
      bf[ni] = c.s;
    }
#pragma unroll
    for (int mi = 0; mi < 4; ++mi)
#pragma unroll
      for (int ni = 0; ni < 4; ++ni)
        acc[mi][ni] = __builtin_amdgcn_mfma_f32_16x16x32_bf16(rK[mi][kt], bf[ni], acc[mi][ni], 0, 0, 0);
  }

#pragma unroll
  for (int mi = 0; mi < 4; ++mi)
#pragma unroll
    for (int ni = 0; ni < 4; ++ni) {
      int node = tile0 * 64 + ni * 16 + lp;
      if (node < N) {
        int r0 = w * 64 + mi * 16 + quad * 4;
        v4f v = acc[mi][ni];
        if (isU) {
          v2u pw; pw.x = pk2(v[0] + rbb[mi][0], v[1] + rbb[mi][1]);
          pw.y = pk2(v[2] + rbb[mi][2], v[3] + rbb[mi][3]);
          *(v2u*)(HuT + (size_t)node * 256 + r0) = pw;
        } else {
          *(v4f*)(HmT + (size_t)node * 256 + r0) = v;
        }
      }
    }
}

// ===================== main fused kernel (precomputed-H path) =====================
#define LDHROW 256           // shorts per H row, unpadded; XOR slot-swizzle
#define HBUF2 (64 * LDHROW)  // 16384 shorts / buffer
#define LDP_S 20             // 16 slots + 4 pad floats
#define PBUF (64 * LDP_S)
#define SMEM2 (2*HBUF2*2 + 2*PBUF*4)   // 75776 B

// Roles: 4 G-waves (gather Hu/Hm + add/relu/commit H + P-store) carry no MFMA;
// 4 C-waves run the proven v9 L2+W3 loop (mi=4, rW2 resident). Per-SIMD MFMA
// load drops from 192 to 128 MFMA/phase; L1 MFMAs + X pipeline are gone.
// H rows are slot-swizzled: 16B-slot' = slot ^ (row&15). C-reads stay at the
// free 2-way minimum; G-commit writes drop from 8-way to 2-way.
// Phase k (one barrier): G commits H(t_k)->ldsH[pb], prefetches t_{k+1};
// C computes L2(t_{k-1}) from ldsH[pb^1] -> ldsP[pb^1]; G wg0 stores P(t_{k-2})
// from ldsP[pb].
__global__ __launch_bounds__(512, 2) void mlp_v11(
    const short* __restrict__ HuT, const float* __restrict__ HmT,
    const void* __restrict__ eidx,
    const short* __restrict__ pW2,
    const float* __restrict__ b2, const float* __restrict__ W3,
    const float* __restrict__ b3, float* __restrict__ out, int E)
{
  extern __shared__ __align__(16) char smem[];
  short* ldsH = (short*)smem;                        // [2][HBUF2]
  float* ldsP = (float*)(smem + 2 * HBUF2 * 2);      // [2][PBUF]

  const int t    = threadIdx.x;
  const int w    = t >> 6;
  const int lane = t & 63;
  const int quad = lane >> 4;
  const int lp   = lane & 15;
  const int wg   = w >> 1;
  const bool isG = (((w & 1) ^ ((w >> 2) & 1)) == 0);

  // ---- index dtype detection: int64 iff odd 32-bit words are all zero
  const unsigned* ew = (const unsigned*)eidx;
  unsigned oddw = (lane < 32) ? ew[2 * lane + 1] : 0u;
  const bool i64 = (__ballot(oddw != 0u) == 0ull);

  const int ntiles = (E + 63) >> 6;
  const int S   = (int)gridDim.x;
  const int bid = (int)blockIdx.x;
  const int Tb  = (ntiles - bid + S - 1) / S;
  const float bias3 = b3[0];

  if (isG) {
    // =============== gather/commit waves (no MFMA) ===============
    const int ra = wg * 64 + lane;    // 0..255 : 4 threads/edge
    const int gi = ra >> 2;           // edge in tile
    const int q  = ra & 3;            // hidden chunk q*64..q*64+63

    auto loadIdx = [&](int tl, int& row, int& col) {
      int gE = tl * 64 + gi;
      if (gE >= E || gE < 0) gE = 0;
      if (i64) {
        const long long* p = (const long long*)eidx;
        row = (int)p[gE]; col = (int)p[(long long)E + gE];
      } else {
        const int* p = (const int*)eidx;
        row = p[gE]; col = p[E + gE];
      }
    };

    v4u hu[8];    // 64 bf16 of Hu row chunk
    v4f hm[16];   // 64 f32  of Hm row chunk
    auto issueG = [&](int row, int col) {
      const v4u* pu = (const v4u*)(HuT + (size_t)row * 256 + q * 64);
#pragma unroll
      for (int j = 0; j < 8; ++j) hu[j] = pu[j];
      const v4f* pm = (const v4f*)(HmT + (size_t)col * 256 + q * 64);
#pragma unroll
      for (int j = 0; j < 16; ++j) hm[j] = pm[j];
    };

    int rowN, colN;
    loadIdx(bid, rowN, colN);
    issueG(rowN, colN);
    loadIdx(bid + S, rowN, colN);

    for (int k = 0; k <= Tb + 1; ++k) {
      __syncthreads();
      const int pb = k & 1;
      const int tg = bid + k * S;

      // ---- commit H(tg) = relu(hu + hm) -> ldsH[pb], slot-swizzled
      if (k < Tb) {
        short* hb = &ldsH[pb * HBUF2 + gi * LDHROW];
        const int sw = gi & 15;
#pragma unroll
        for (int j = 0; j < 8; ++j) {
          v4u u = hu[j];
          v4u o;
#pragma unroll
          for (int d = 0; d < 4; ++d) {
            const int e = j * 8 + d * 2;
            float s0 = bflo(u[d]) + hm[e >> 2][e & 3];
            float s1 = bfhi(u[d]) + hm[(e + 1) >> 2][(e + 1) & 3];
            o[d] = pk2(fmaxf(s0, 0.f), fmaxf(s1, 0.f));
          }
          const int slot = (8 * q + j) ^ sw;
          *(v4u*)(hb + slot * 8) = o;
        }
      }
      // ---- prefetch gather(t_{k+1}), indices(t_{k+2})
      if (k + 1 < Tb) {
        issueG(rowN, colN);
        loadIdx(tg + 2 * S, rowN, colN);
      }
      // ---- reduce + store tile t2 from ldsP[pb] (wave wg==0, lane = edge)
      const int t2 = tg - 2 * S;
      if (t2 >= 0 && wg == 0) {
        const v4f* pp = (const v4f*)&ldsP[pb * PBUF + lane * LDP_S];
        float r = bias3;
#pragma unroll
        for (int c = 0; c < 4; ++c) {
          v4f p = pp[c];
          r += (p[0] + p[1]) + (p[2] + p[3]);
        }
        int o = t2 * 64 + lane;
        if (o < E) out[o] = r;
      }
    }
  } else {
    // =============== consumer: layer 2 + bias/ReLU + W3 fold ===============
    const v8s* w2v = (const v8s*)pW2;
    v8s rW2[4][8];                     // 128 VGPR: out rows wg*64..wg*64+63
#pragma unroll
    for (int mi = 0; mi < 4; ++mi)
#pragma unroll
      for (int kt = 0; kt < 8; ++kt)
        rW2[mi][kt] = w2v[(((wg * 4 + mi) * 8) + kt) * 64 + lane];
    v4f rb2[4], rw3[4];
#pragma unroll
    for (int mi = 0; mi < 4; ++mi) {
      int nh0 = wg * 64 + mi * 16 + quad * 4;
      rb2[mi] = *(const v4f*)(b2 + nh0);
      rw3[mi] = *(const v4f*)(W3 + nh0);
    }

    for (int k = 0; k <= Tb + 1; ++k) {
      __syncthreads();
      const int pb = k & 1;
      const int tg = bid + k * S;
      const int t1 = tg - S;
      if (t1 >= 0 && t1 < ntiles) {
        const short* hbr = &ldsH[(pb ^ 1) * HBUF2];
        float* pPw = &ldsP[(pb ^ 1) * PBUF];
#pragma unroll 1
        for (int nh = 0; nh < 2; ++nh) {       // ni halves: acc live = 32 VGPR
          v4f acc2[4][2];
#pragma unroll
          for (int mi = 0; mi < 4; ++mi) { acc2[mi][0] = rb2[mi]; acc2[mi][1] = rb2[mi]; }
          __builtin_amdgcn_s_setprio(1);
#pragma unroll
          for (int kt = 0; kt < 8; ++kt) {
            // row = (nh*2+nj)*16+lp ; 16B-slot = (kt*4+quad) ^ (row&15) = ^lp
            v8s bf0 = *(const v8s*)&hbr[((nh * 2 + 0) * 16 + lp) * LDHROW + ((kt * 4 + quad) ^ lp) * 8];
            v8s bf1 = *(const v8s*)&hbr[((nh * 2 + 1) * 16 + lp) * LDHROW + ((kt * 4 + quad) ^ lp) * 8];
#pragma unroll
            for (int mi = 0; mi < 4; ++mi) {
              acc2[mi][0] = __builtin_amdgcn_mfma_f32_16x16x32_bf16(rW2[mi][kt], bf0, acc2[mi][0], 0, 0, 0);
              acc2[mi][1] = __builtin_amdgcn_mfma_f32_16x16x32_bf16(rW2[mi][kt], bf1, acc2[mi][1], 0, 0, 0);
            }
          }
          __builtin_amdgcn_s_setprio(0);
          float s0 = 0.f, s1 = 0.f;
#pragma unroll
          for (int mi = 0; mi < 4; ++mi) {
#pragma unroll
            for (int r = 0; r < 4; ++r) {
              s0 += fmaxf(acc2[mi][0][r], 0.f) * rw3[mi][r];
              s1 += fmaxf(acc2[mi][1][r], 0.f) * rw3[mi][r];
            }
          }
          int e0 = (nh * 2 + 0) * 16 + lp, e1 = (nh * 2 + 1) * 16 + lp;
          pPw[e0 * LDP_S + wg * 4 + quad] = s0;
          pPw[e1 * LDP_S + wg * 4 + quad] = s1;
        }
      }
    }
  }
}

// ===================== fallback (proven v9, used if workspace too small) =====================
#define LDX_S 136
#define LDH_S 264
#define XBUF (64 * LDX_S)
#define HBUF (64 * LDH_S)
#define SMEM_BYTES (2*XBUF*2 + 2*HBUF*2 + 2*PBUF*4)   // 112640

__global__ __launch_bounds__(512, 2) void mlp_v9(
    const float* __restrict__ xu, const float* __restrict__ xm,
    const void* __restrict__ eidx,
    const short* __restrict__ pW1, const short* __restrict__ pW2,
    const float* __restrict__ b1, const float* __restrict__ b2,
    const float* __restrict__ W3, const float* __restrict__ b3,
    float* __restrict__ out, int E)
{
  extern __shared__ __align__(16) char smem[];
  short* ldsX = (short*)smem;
  short* ldsH = (short*)(smem + 2 * XBUF * 2);
  float* ldsP = (float*)(smem + 2 * XBUF * 2 + 2 * HBUF * 2);

  const int t    = threadIdx.x;
  const int w    = t >> 6;
  const int lane = t & 63;
  const int quad = lane >> 4;
  const int lp   = lane & 15;
  const int wg   = w >> 1;
  const bool isA = (((w & 1) ^ ((w >> 2) & 1)) == 0);

  const unsigned* ew = (const unsigned*)eidx;
  unsigned oddw = (lane < 32) ? ew[2 * lane + 1] : 0u;
  const bool i64 = (__ballot(oddw != 0u) == 0ull);

  const int ntiles = (E + 63) >> 6;
  const int S   = (int)gridDim.x;
  const int bid = (int)blockIdx.x;
  const int Tb  = (ntiles - bid + S - 1) / S;
  const float bias3 = b3[0];

  if (isA) {
    const v8s* w1v = (const v8s*)pW1;
    v8s rW1[4][4];
#pragma unroll
    for (int mi = 0; mi < 4; ++mi)
#pragma unroll
      for (int kt = 0; kt < 4; ++kt)
        rW1[mi][kt] = w1v[(((wg * 4 + mi) * 4) + kt) * 64 + lane];
    v4f rb1[4];
#pragma unroll
    for (int mi = 0; mi < 4; ++mi)
      rb1[mi] = *(const v4f*)(b1 + wg * 64 + mi * 16 + quad * 4);

    const int ra = wg * 64 + lane;
    const int gi = ra >> 2, gq = ra & 3;

    auto loadIdx = [&](int tl, int& row, int& col) {
      int gE = tl * 64 + gi;
      if (gE >= E || gE < 0) gE = 0;
      if (i64) {
        const long long* p = (const long long*)eidx;
        row = (int)p[gE]; col = (int)p[(long long)E + gE];
      } else {
        const int* p = (const int*)eidx;
        row = p[gE]; col = p[E + gE];
      }
    };

    v4f U0, U1, U2, U3, M0, M1, M2, M3;
    auto issueUM = [&](int row, int col) {
      const v4f* pu = (const v4f*)(xu + (size_t)row * 64 + gq * 16);
      const v4f* pm = (const v4f*)(xm + (size_t)col * 64 + gq * 16);
      U0 = pu[0]; U1 = pu[1]; U2 = pu[2]; U3 = pu[3];
      M0 = pm[0]; M1 = pm[1]; M2 = pm[2]; M3 = pm[3];
    };

    int rowN, colN;
    loadIdx(bid, rowN, colN);
    issueUM(rowN, colN);
    loadIdx(bid + S, rowN, colN);

    for (int k = 0; k <= Tb + 2; ++k) {
      __syncthreads();
      const int pb = k & 1;
      const int tg = bid + k * S;

      if (k < Tb) {
        short* px = &ldsX[pb * XBUF + gi * LDX_S + gq * 16];
        v4u a0 = { pk2(U0[0], U0[1]), pk2(U0[2], U0[3]),
                   pk2(U1[0], U1[1]), pk2(U1[2], U1[3]) };
        v4u a1 = { pk2(U2[0], U2[1]), pk2(U2[2], U2[3]),
                   pk2(U3[0], U3[1]), pk2(U3[2], U3[3]) };
        v4u c0 = { pk2(M0[0], M0[1]), pk2(M0[2], M0[3]),
                   pk2(M1[0], M1[1]), pk2(M1[2], M1[3]) };
        v4u c1 = { pk2(M2[0], M2[1]), pk2(M2[2], M2[3]),
                   pk2(M3[0], M3[1]), pk2(M3[2], M3[3]) };
        *(v4u*)(px)      = a0;  *(v4u*)(px + 8)  = a1;
        *(v4u*)(px + 64) = c0;  *(v4u*)(px + 72) = c1;
      }
      if (k + 1 < Tb) {
        issueUM(rowN, colN);
        loadIdx(tg + 2 * S, rowN, colN);
      }

      const int t3 = tg - 3 * S;
      if (t3 >= 0 && wg == 0) {
        const v4f* pp = (const v4f*)&ldsP[(pb ^ 1) * PBUF + lane * LDP_S];
        float r = bias3;
#pragma unroll
        for (int c = 0; c < 4; ++c) {
          v4f p = pp[c];
          r += (p[0] + p[1]) + (p[2] + p[3]);
        }
        int o = t3 * 64 + lane;
        if (o < E) out[o] = r;
      }

      const int t1 = tg - S;
      if (t1 >= 0 && t1 < ntiles) {
        const short* xb = &ldsX[(pb ^ 1) * XBUF];
        short* hb = &ldsH[(pb ^ 1) * HBUF];
#pragma unroll 1
        for (int nh = 0; nh < 2; ++nh) {
          v4f acc[4][2];
#pragma unroll
          for (int mi = 0; mi < 4; ++mi) { acc[mi][0] = rb1[mi]; acc[mi][1] = rb1[mi]; }
          __builtin_amdgcn_s_setprio(1);
#pragma unroll
          for (int kt = 0; kt < 4; ++kt) {
            v8s bf0 = *(const v8s*)&xb[((nh * 2 + 0) * 16 + lp) * LDX_S + kt * 32 + quad * 8];
            v8s bf1 = *(const v8s*)&xb[((nh * 2 + 1) * 16 + lp) * LDX_S + kt * 32 + quad * 8];
#pragma unroll
            for (int mi = 0; mi < 4; ++mi) {
              acc[mi][0] = __builtin_amdgcn_mfma_f32_16x16x32_bf16(rW1[mi][kt], bf0, acc[mi][0], 0, 0, 0);
              acc[mi][1] = __builtin_amdgcn_mfma_f32_16x16x32_bf16(rW1[mi][kt], bf1, acc[mi][1], 0, 0, 0);
            }
          }
          __builtin_amdgcn_s_setprio(0);
#pragma unroll
          for (int mi = 0; mi < 4; ++mi) {
            int nh0 = wg * 64 + mi * 16 + quad * 4;
#pragma unroll
            for (int nj = 0; nj < 2; ++nj) {
              int e = (nh * 2 + nj) * 16 + lp;
              v4f v = acc[mi][nj];
              v2u pw; pw.x = pk2(fmaxf(v[0], 0.f), fmaxf(v[1], 0.f));
              pw.y = pk2(fmaxf(v[2], 0.f), fmaxf(v[3], 0.f));
              *(v2u*)&hb[e * LDH_S + nh0] = pw;
            }
          }
        }
      }
    }
  } else {
    const v8s* w2v = (const v8s*)pW2;
    v8s rW2[4][8];
#pragma unroll
    for (int mi = 0; mi < 4; ++mi)
#pragma unroll
      for (int kt = 0; kt < 8; ++kt)
        rW2[mi][kt] = w2v[(((wg * 4 + mi) * 8) + kt) * 64 + lane];
    v4f rb2[4], rw3[4];
#pragma unroll
    for (int mi = 0; mi < 4; ++mi) {
      int nh0 = wg * 64 + mi * 16 + quad * 4;
      rb2[mi] = *(const v4f*)(b2 + nh0);
      rw3[mi] = *(const v4f*)(W3 + nh0);
    }

    for (int k = 0; k <= Tb + 2; ++k) {
      __syncthreads();
      const int pb = k & 1;
      const int tg = bid + k * S;
      const int t2 = tg - 2 * S;
      if (t2 >= 0 && t2 < ntiles) {
        const short* hbr = &ldsH[pb * HBUF];
        float* pPw = &ldsP[pb * PBUF];
#pragma unroll 1
        for (int nh = 0; nh < 2; ++nh) {
          v4f acc2[4][2];
#pragma unroll
          for (int mi = 0; mi < 4; ++mi) { acc2[mi][0] = rb2[mi]; acc2[mi][1] = rb2[mi]; }
          __builtin_amdgcn_s_setprio(1);
#pragma unroll
          for (int kt = 0; kt < 8; ++kt) {
            v8s bf0 = *(const v8s*)&hbr[((nh * 2 + 0) * 16 + lp) * LDH_S + kt * 32 + quad * 8];
            v8s bf1 = *(const v8s*)&hbr[((nh * 2 + 1) * 16 + lp) * LDH_S + kt * 32 + quad * 8];
#pragma unroll
            for (int mi = 0; mi < 4; ++mi) {
              acc2[mi][0] = __builtin_amdgcn_mfma_f32_16x16x32_bf16(rW2[mi][kt], bf0, acc2[mi][0], 0, 0, 0);
              acc2[mi][1] = __builtin_amdgcn_mfma_f32_16x16x32_bf16(rW2[mi][kt], bf1, acc2[mi][1], 0, 0, 0);
            }
          }
          __builtin_amdgcn_s_setprio(0);
          float s0 = 0.f, s1 = 0.f;
#pragma unroll
          for (int mi = 0; mi < 4; ++mi) {
#pragma unroll
            for (int r = 0; r < 4; ++r) {
              s0 += fmaxf(acc2[mi][0][r], 0.f) * rw3[mi][r];
              s1 += fmaxf(acc2[mi][1][r], 0.f) * rw3[mi][r];
            }
          }
          int e0 = (nh * 2 + 0) * 16 + lp, e1 = (nh * 2 + 1) * 16 + lp;
          pPw[e0 * LDP_S + wg * 4 + quad] = s0;
          pPw[e1 * LDP_S + wg * 4 + quad] = s1;
        }
      }
    }
  }
}

extern "C" void kernel_launch(void* const* d_in, const int* in_sizes, int n_in,
                              void* d_out, int out_size, void* d_ws, size_t ws_size,
                              hipStream_t stream) {
  const float* xu  = (const float*)d_in[0];
  const float* xm  = (const float*)d_in[1];
  const void*  ei  = d_in[2];
  const float* W1  = (const float*)d_in[3];
  const float* b1  = (const float*)d_in[4];
  const float* W2  = (const float*)d_in[5];
  const float* b2  = (const float*)d_in[6];
  const float* W3  = (const float*)d_in[7];
  const float* b3  = (const float*)d_in[8];
  float* out = (float*)d_out;

  const int E  = in_sizes[2] / 2;
  const int Nu = in_sizes[0] / 64;
  const int Nm = in_sizes[1] / 64;

  short* pW1 = (short*)d_ws;          // 64 KB
  short* pW2 = pW1 + 32768;           // 128 KB

  hipLaunchKernelGGL(pack_weights, dim3(384), dim3(256), 0, stream, W1, W2, pW1, pW2);

  const int ntiles = (E + 63) / 64;
  const int nblk = ntiles < 256 ? ntiles : 256;

  const size_t huBytes = (size_t)Nu * 512;    // bf16 [Nu][256]
  const size_t hmBytes = (size_t)Nm * 1024;   // f32  [Nm][256]
  const size_t need = 196608 + huBytes + hmBytes;

  if (ws_size >= need && Nu > 0 && Nm > 0) {
    short* HuT = (short*)((char*)d_ws + 196608);
    float* HmT = (float*)((char*)HuT + huBytes);
    const int NU64 = (Nu + 63) / 64, NM64 = (Nm + 63) / 64;

    hipLaunchKernelGGL(make_h, dim3(NU64 + NM64), dim3(256), 0, stream,
                       xu, xm, pW1, b1, HuT, HmT, Nu, Nm, NU64);

    hipFuncSetAttribute((const void*)mlp_v11,
                        hipFuncAttributeMaxDynamicSharedMemorySize, SMEM2);
    hipLaunchKernelGGL(mlp_v11, dim3(nblk), dim3(512), SMEM2, stream,
                       HuT, HmT, ei, pW2, b2, W3, b3, out, E);
  } else {
    hipFuncSetAttribute((const void*)mlp_v9,
                        hipFuncAttributeMaxDynamicSharedMemorySize, SMEM_BYTES);
    hipLaunchKernelGGL(mlp_v9, dim3(nblk), dim3(512), SMEM_BYTES, stream,
                       xu, xm, ei, pW1, pW2, b1, b2, W3, b3, out, E);
  }
}

// Round 4
// 237.048 us; speedup vs baseline: 1.4509x; 1.4509x over previous
//
#include <hip/hip_runtime.h>
#include <hip/hip_bf16.h>

typedef __attribute__((ext_vector_type(4))) float v4f;
typedef __attribute__((ext_vector_type(8))) short v8s;
typedef __attribute__((ext_vector_type(4))) unsigned v4u;
typedef __attribute__((ext_vector_type(2))) unsigned v2u;

// full RNE fp32->bf16 (prep kernel only)
__device__ __forceinline__ short f2bf(float f) {
  union { float f; unsigned u; } v; v.f = f;
  unsigned r = v.u + 0x7FFFu + ((v.u >> 16) & 1u);
  return (short)(r >> 16);
}
// packed 2xfp32 -> bf16x2, single v_cvt_pk_bf16_f32
__device__ __forceinline__ unsigned pk2(float a, float b) {
  union { __hip_bfloat162 h; unsigned u; } c;
  c.h = __float22bfloat162_rn(make_float2(a, b));
  return c.u;
}

// prep: pack W1 [128x256] + W2 [256x256] into MFMA A-fragment order (bf16),
// AND convert x_user/x_movie f32 -> bf16 feature tables (RNE, identical to
// the in-register conversion the edge kernel used to do -> bit-identical
// numerics, half the gather bytes, 19.2 MB L2/L3-resident working set).
__global__ void prep(const float* __restrict__ W1, const float* __restrict__ W2,
                     const float* __restrict__ xu, const float* __restrict__ xm,
                     short* __restrict__ pW1, short* __restrict__ pW2,
                     short* __restrict__ xub, short* __restrict__ xmb,
                     int Nu, int Nm) {
  int tid = blockIdx.x * 256 + threadIdx.x;
  if (tid < 32768) {
    int j = tid & 7, l = (tid >> 3) & 63, frag = tid >> 9;
    int mt = frag >> 2, kt = frag & 3;
    int n = mt * 16 + (l & 15);
    int k = kt * 32 + ((l >> 4) * 8) + j;
    pW1[tid] = f2bf(W1[k * 256 + n]);
  } else if (tid < 98304) {
    int t2 = tid - 32768;
    int j = t2 & 7, l = (t2 >> 3) & 63, frag = t2 >> 9;
    int mt = frag >> 3, kt = frag & 7;
    int n = mt * 16 + (l & 15);
    int k = kt * 32 + ((l >> 4) * 8) + j;
    pW2[t2] = f2bf(W2[k * 256 + n]);
  } else {
    // conversion region: one 8-float chunk per thread
    int c = tid - 98304;
    int tu = Nu * 8;
    int total = tu + Nm * 8;
    if (c < total) {
      const float* s; short* d;
      if (c < tu) { s = xu + (size_t)c * 8; d = xub + (size_t)c * 8; }
      else { int c2 = c - tu; s = xm + (size_t)c2 * 8; d = xmb + (size_t)c2 * 8; }
      v4f a = *(const v4f*)s, b = *(const v4f*)(s + 4);
      v4u o = { pk2(a[0], a[1]), pk2(a[2], a[3]), pk2(b[0], b[1]), pk2(b[2], b[3]) };
      *(v4u*)d = o;
    }
  }
}

#define LDX_S 136   // 128 + 8 pad shorts
#define LDH_S 264   // 256 + 8 pad shorts
#define LDP_S 20    // 16 slots + 4 pad floats
#define XBUF (64 * LDX_S)   // 8704 shorts / buffer
#define HBUF (64 * LDH_S)   // 16896 shorts / buffer
#define PBUF (64 * LDP_S)   // 1280 floats / buffer
#define SMEM_BYTES (2*XBUF*2 + 2*HBUF*2 + 2*PBUF*4)   // 112640

// v12 = v9 (proven 183 us) with bf16 feature-table gather: 128 B/side/edge
// instead of 256 B, no per-phase cvt VALU on A-waves, working set 19.2 MB
// (cache-resident) instead of 38.4 MB. Structure unchanged:
// 4 A-waves (gather+commit X, L1 MFMA, P-store on wg0) + 4 B-waves (L2+W3),
// one A + one B per SIMD; single-barrier 3-deep pipeline, double buffers.
__global__ __launch_bounds__(512, 2) void mlp_v12(
    const short* __restrict__ xub, const short* __restrict__ xmb,
    const void* __restrict__ eidx,
    const short* __restrict__ pW1, const short* __restrict__ pW2,
    const float* __restrict__ b1, const float* __restrict__ b2,
    const float* __restrict__ W3, const float* __restrict__ b3,
    float* __restrict__ out, int E)
{
  extern __shared__ __align__(16) char smem[];
  short* ldsX = (short*)smem;                       // [2][XBUF]
  short* ldsH = (short*)(smem + 2 * XBUF * 2);      // [2][HBUF]
  float* ldsP = (float*)(smem + 2 * XBUF * 2 + 2 * HBUF * 2); // [2][PBUF]

  const int t    = threadIdx.x;
  const int w    = t >> 6;
  const int lane = t & 63;
  const int quad = lane >> 4;
  const int lp   = lane & 15;
  const int wg   = w >> 1;
  const bool isA = (((w & 1) ^ ((w >> 2) & 1)) == 0);

  const unsigned* ew = (const unsigned*)eidx;
  unsigned oddw = (lane < 32) ? ew[2 * lane + 1] : 0u;
  const bool i64 = (__ballot(oddw != 0u) == 0ull);

  const int ntiles = (E + 63) >> 6;
  const int S   = (int)gridDim.x;
  const int bid = (int)blockIdx.x;
  const int Tb  = (ntiles - bid + S - 1) / S;
  const float bias3 = b3[0];

  if (isA) {
    // ===== producer: gather (bf16) + layer 1 (+ store on wg==0) =====
    const v8s* w1v = (const v8s*)pW1;
    v8s rW1[4][4];
#pragma unroll
    for (int mi = 0; mi < 4; ++mi)
#pragma unroll
      for (int kt = 0; kt < 4; ++kt)
        rW1[mi][kt] = w1v[(((wg * 4 + mi) * 4) + kt) * 64 + lane];
    v4f rb1[4];
#pragma unroll
    for (int mi = 0; mi < 4; ++mi)
      rb1[mi] = *(const v4f*)(b1 + wg * 64 + mi * 16 + quad * 4);

    const int ra = wg * 64 + lane;      // A-rank 0..255 : 4 threads/edge
    const int gi = ra >> 2, gq = ra & 3;

    auto loadIdx = [&](int tl, int& row, int& col) {
      int gE = tl * 64 + gi;
      if (gE >= E || gE < 0) gE = 0;
      if (i64) {
        const long long* p = (const long long*)eidx;
        row = (int)p[gE]; col = (int)p[(long long)E + gE];
      } else {
        const int* p = (const int*)eidx;
        row = p[gE]; col = p[E + gE];
      }
    };

    v4u u0, u1, m0, m1;   // 16 bf16 per side, already converted
    auto issueUM = [&](int row, int col) {
      const v4u* pu = (const v4u*)(xub + (size_t)row * 64 + gq * 16);
      const v4u* pm = (const v4u*)(xmb + (size_t)col * 64 + gq * 16);
      u0 = pu[0]; u1 = pu[1]; m0 = pm[0]; m1 = pm[1];
    };

    int rowN, colN;
    loadIdx(bid, rowN, colN);
    issueUM(rowN, colN);
    loadIdx(bid + S, rowN, colN);

    for (int k = 0; k <= Tb + 2; ++k) {
      __syncthreads();
      const int pb = k & 1;
      const int tg = bid + k * S;

      // ---- commit prefetched bf16 features -> ldsX[pb] (no cvt needed)
      if (k < Tb) {
        short* px = &ldsX[pb * XBUF + gi * LDX_S + gq * 16];
        *(v4u*)(px)      = u0;  *(v4u*)(px + 8)  = u1;   // user  -> k 0..63
        *(v4u*)(px + 64) = m0;  *(v4u*)(px + 72) = m1;   // movie -> k 64..127
      }
      // ---- prefetch features(t_{k+1}), indices(t_{k+2})
      if (k + 1 < Tb) {
        issueUM(rowN, colN);
        loadIdx(tg + 2 * S, rowN, colN);
      }

      // ---- reduce + store tile t3 from ldsP[pb^1] (wave wg==0, lane = edge)
      const int t3 = tg - 3 * S;
      if (t3 >= 0 && wg == 0) {
        const v4f* pp = (const v4f*)&ldsP[(pb ^ 1) * PBUF + lane * LDP_S];
        float r = bias3;
#pragma unroll
        for (int c = 0; c < 4; ++c) {
          v4f p = pp[c];
          r += (p[0] + p[1]) + (p[2] + p[3]);
        }
        int o = t3 * 64 + lane;
        if (o < E) out[o] = r;
      }

      // ---- layer 1 of t1 : ldsX[pb^1] -> ldsH[pb^1]
      const int t1 = tg - S;
      if (t1 >= 0 && t1 < ntiles) {
        const short* xb = &ldsX[(pb ^ 1) * XBUF];
        short* hb = &ldsH[(pb ^ 1) * HBUF];
#pragma unroll 1
        for (int nh = 0; nh < 2; ++nh) {       // ni halves: acc live = 32 VGPR
          v4f acc[4][2];
#pragma unroll
          for (int mi = 0; mi < 4; ++mi) { acc[mi][0] = rb1[mi]; acc[mi][1] = rb1[mi]; }
          __builtin_amdgcn_s_setprio(1);
#pragma unroll
          for (int kt = 0; kt < 4; ++kt) {
            v8s bf0 = *(const v8s*)&xb[((nh * 2 + 0) * 16 + lp) * LDX_S + kt * 32 + quad * 8];
            v8s bf1 = *(const v8s*)&xb[((nh * 2 + 1) * 16 + lp) * LDX_S + kt * 32 + quad * 8];
#pragma unroll
            for (int mi = 0; mi < 4; ++mi) {
              acc[mi][0] = __builtin_amdgcn_mfma_f32_16x16x32_bf16(rW1[mi][kt], bf0, acc[mi][0], 0, 0, 0);
              acc[mi][1] = __builtin_amdgcn_mfma_f32_16x16x32_bf16(rW1[mi][kt], bf1, acc[mi][1], 0, 0, 0);
            }
          }
          __builtin_amdgcn_s_setprio(0);
#pragma unroll
          for (int mi = 0; mi < 4; ++mi) {
            int nh0 = wg * 64 + mi * 16 + quad * 4;
#pragma unroll
            for (int nj = 0; nj < 2; ++nj) {
              int e = (nh * 2 + nj) * 16 + lp;
              v4f v = acc[mi][nj];
              v2u pw; pw.x = pk2(fmaxf(v[0], 0.f), fmaxf(v[1], 0.f));
              pw.y = pk2(fmaxf(v[2], 0.f), fmaxf(v[3], 0.f));
              *(v2u*)&ldsH[(pb ^ 1) * HBUF + e * LDH_S + nh0] = pw;
            }
          }
        }
        (void)hb;
      }
    }
  } else {
    // ===== consumer: layer 2 + bias/ReLU + W3 fold =====
    const v8s* w2v = (const v8s*)pW2;
    v8s rW2[4][8];
#pragma unroll
    for (int mi = 0; mi < 4; ++mi)
#pragma unroll
      for (int kt = 0; kt < 8; ++kt)
        rW2[mi][kt] = w2v[(((wg * 4 + mi) * 8) + kt) * 64 + lane];
    v4f rb2[4], rw3[4];
#pragma unroll
    for (int mi = 0; mi < 4; ++mi) {
      int nh0 = wg * 64 + mi * 16 + quad * 4;
      rb2[mi] = *(const v4f*)(b2 + nh0);
      rw3[mi] = *(const v4f*)(W3 + nh0);
    }

    for (int k = 0; k <= Tb + 2; ++k) {
      __syncthreads();
      const int pb = k & 1;
      const int tg = bid + k * S;
      const int t2 = tg - 2 * S;
      if (t2 >= 0 && t2 < ntiles) {
        const short* hbr = &ldsH[pb * HBUF];
        float* pPw = &ldsP[pb * PBUF];
#pragma unroll 1
        for (int nh = 0; nh < 2; ++nh) {
          v4f acc2[4][2];
#pragma unroll
          for (int mi = 0; mi < 4; ++mi) { acc2[mi][0] = rb2[mi]; acc2[mi][1] = rb2[mi]; }
          __builtin_amdgcn_s_setprio(1);
#pragma unroll
          for (int kt = 0; kt < 8; ++kt) {
            v8s bf0 = *(const v8s*)&hbr[((nh * 2 + 0) * 16 + lp) * LDH_S + kt * 32 + quad * 8];
            v8s bf1 = *(const v8s*)&hbr[((nh * 2 + 1) * 16 + lp) * LDH_S + kt * 32 + quad * 8];
#pragma unroll
            for (int mi = 0; mi < 4; ++mi) {
              acc2[mi][0] = __builtin_amdgcn_mfma_f32_16x16x32_bf16(rW2[mi][kt], bf0, acc2[mi][0], 0, 0, 0);
              acc2[mi][1] = __builtin_amdgcn_mfma_f32_16x16x32_bf16(rW2[mi][kt], bf1, acc2[mi][1], 0, 0, 0);
            }
          }
          __builtin_amdgcn_s_setprio(0);
          float s0 = 0.f, s1 = 0.f;
#pragma unroll
          for (int mi = 0; mi < 4; ++mi) {
#pragma unroll
            for (int r = 0; r < 4; ++r) {
              s0 += fmaxf(acc2[mi][0][r], 0.f) * rw3[mi][r];
              s1 += fmaxf(acc2[mi][1][r], 0.f) * rw3[mi][r];
            }
          }
          int e0 = (nh * 2 + 0) * 16 + lp, e1 = (nh * 2 + 1) * 16 + lp;
          pPw[e0 * LDP_S + wg * 4 + quad] = s0;
          pPw[e1 * LDP_S + wg * 4 + quad] = s1;
        }
      }
    }
  }
}

// ===== fallback (v9 verbatim, f32 gather) -- only if workspace < 19.4 MB =====
__global__ __launch_bounds__(512, 2) void mlp_v9(
    const float* __restrict__ xu, const float* __restrict__ xm,
    const void* __restrict__ eidx,
    const short* __restrict__ pW1, const short* __restrict__ pW2,
    const float* __restrict__ b1, const float* __restrict__ b2,
    const float* __restrict__ W3, const float* __restrict__ b3,
    float* __restrict__ out, int E)
{
  extern __shared__ __align__(16) char smem[];
  short* ldsX = (short*)smem;
  short* ldsH = (short*)(smem + 2 * XBUF * 2);
  float* ldsP = (float*)(smem + 2 * XBUF * 2 + 2 * HBUF * 2);

  const int t    = threadIdx.x;
  const int w    = t >> 6;
  const int lane = t & 63;
  const int quad = lane >> 4;
  const int lp   = lane & 15;
  const int wg   = w >> 1;
  const bool isA = (((w & 1) ^ ((w >> 2) & 1)) == 0);

  const unsigned* ew = (const unsigned*)eidx;
  unsigned oddw = (lane < 32) ? ew[2 * lane + 1] : 0u;
  const bool i64 = (__ballot(oddw != 0u) == 0ull);

  const int ntiles = (E + 63) >> 6;
  const int S   = (int)gridDim.x;
  const int bid = (int)blockIdx.x;
  const int Tb  = (ntiles - bid + S - 1) / S;
  const float bias3 = b3[0];

  if (isA) {
    const v8s* w1v = (const v8s*)pW1;
    v8s rW1[4][4];
#pragma unroll
    for (int mi = 0; mi < 4; ++mi)
#pragma unroll
      for (int kt = 0; kt < 4; ++kt)
        rW1[mi][kt] = w1v[(((wg * 4 + mi) * 4) + kt) * 64 + lane];
    v4f rb1[4];
#pragma unroll
    for (int mi = 0; mi < 4; ++mi)
      rb1[mi] = *(const v4f*)(b1 + wg * 64 + mi * 16 + quad * 4);

    const int ra = wg * 64 + lane;
    const int gi = ra >> 2, gq = ra & 3;

    auto loadIdx = [&](int tl, int& row, int& col) {
      int gE = tl * 64 + gi;
      if (gE >= E || gE < 0) gE = 0;
      if (i64) {
        const long long* p = (const long long*)eidx;
        row = (int)p[gE]; col = (int)p[(long long)E + gE];
      } else {
        const int* p = (const int*)eidx;
        row = p[gE]; col = p[E + gE];
      }
    };

    v4f U0, U1, U2, U3, M0, M1, M2, M3;
    auto issueUM = [&](int row, int col) {
      const v4f* pu = (const v4f*)(xu + (size_t)row * 64 + gq * 16);
      const v4f* pm = (const v4f*)(xm + (size_t)col * 64 + gq * 16);
      U0 = pu[0]; U1 = pu[1]; U2 = pu[2]; U3 = pu[3];
      M0 = pm[0]; M1 = pm[1]; M2 = pm[2]; M3 = pm[3];
    };

    int rowN, colN;
    loadIdx(bid, rowN, colN);
    issueUM(rowN, colN);
    loadIdx(bid + S, rowN, colN);

    for (int k = 0; k <= Tb + 2; ++k) {
      __syncthreads();
      const int pb = k & 1;
      const int tg = bid + k * S;

      if (k < Tb) {
        short* px = &ldsX[pb * XBUF + gi * LDX_S + gq * 16];
        v4u a0 = { pk2(U0[0], U0[1]), pk2(U0[2], U0[3]),
                   pk2(U1[0], U1[1]), pk2(U1[2], U1[3]) };
        v4u a1 = { pk2(U2[0], U2[1]), pk2(U2[2], U2[3]),
                   pk2(U3[0], U3[1]), pk2(U3[2], U3[3]) };
        v4u c0 = { pk2(M0[0], M0[1]), pk2(M0[2], M0[3]),
                   pk2(M1[0], M1[1]), pk2(M1[2], M1[3]) };
        v4u c1 = { pk2(M2[0], M2[1]), pk2(M2[2], M2[3]),
                   pk2(M3[0], M3[1]), pk2(M3[2], M3[3]) };
        *(v4u*)(px)      = a0;  *(v4u*)(px + 8)  = a1;
        *(v4u*)(px + 64) = c0;  *(v4u*)(px + 72) = c1;
      }
      if (k + 1 < Tb) {
        issueUM(rowN, colN);
        loadIdx(tg + 2 * S, rowN, colN);
      }

      const int t3 = tg - 3 * S;
      if (t3 >= 0 && wg == 0) {
        const v4f* pp = (const v4f*)&ldsP[(pb ^ 1) * PBUF + lane * LDP_S];
        float r = bias3;
#pragma unroll
        for (int c = 0; c < 4; ++c) {
          v4f p = pp[c];
          r += (p[0] + p[1]) + (p[2] + p[3]);
        }
        int o = t3 * 64 + lane;
        if (o < E) out[o] = r;
      }

      const int t1 = tg - S;
      if (t1 >= 0 && t1 < ntiles) {
        const short* xb = &ldsX[(pb ^ 1) * XBUF];
#pragma unroll 1
        for (int nh = 0; nh < 2; ++nh) {
          v4f acc[4][2];
#pragma unroll
          for (int mi = 0; mi < 4; ++mi) { acc[mi][0] = rb1[mi]; acc[mi][1] = rb1[mi]; }
          __builtin_amdgcn_s_setprio(1);
#pragma unroll
          for (int kt = 0; kt < 4; ++kt) {
            v8s bf0 = *(const v8s*)&xb[((nh * 2 + 0) * 16 + lp) * LDX_S + kt * 32 + quad * 8];
            v8s bf1 = *(const v8s*)&xb[((nh * 2 + 1) * 16 + lp) * LDX_S + kt * 32 + quad * 8];
#pragma unroll
            for (int mi = 0; mi < 4; ++mi) {
              acc[mi][0] = __builtin_amdgcn_mfma_f32_16x16x32_bf16(rW1[mi][kt], bf0, acc[mi][0], 0, 0, 0);
              acc[mi][1] = __builtin_amdgcn_mfma_f32_16x16x32_bf16(rW1[mi][kt], bf1, acc[mi][1], 0, 0, 0);
            }
          }
          __builtin_amdgcn_s_setprio(0);
#pragma unroll
          for (int mi = 0; mi < 4; ++mi) {
            int nh0 = wg * 64 + mi * 16 + quad * 4;
#pragma unroll
            for (int nj = 0; nj < 2; ++nj) {
              int e = (nh * 2 + nj) * 16 + lp;
              v4f v = acc[mi][nj];
              v2u pw; pw.x = pk2(fmaxf(v[0], 0.f), fmaxf(v[1], 0.f));
              pw.y = pk2(fmaxf(v[2], 0.f), fmaxf(v[3], 0.f));
              *(v2u*)&ldsH[(pb ^ 1) * HBUF + e * LDH_S + nh0] = pw;
            }
          }
        }
      }
    }
  } else {
    const v8s* w2v = (const v8s*)pW2;
    v8s rW2[4][8];
#pragma unroll
    for (int mi = 0; mi < 4; ++mi)
#pragma unroll
      for (int kt = 0; kt < 8; ++kt)
        rW2[mi][kt] = w2v[(((wg * 4 + mi) * 8) + kt) * 64 + lane];
    v4f rb2[4], rw3[4];
#pragma unroll
    for (int mi = 0; mi < 4; ++mi) {
      int nh0 = wg * 64 + mi * 16 + quad * 4;
      rb2[mi] = *(const v4f*)(b2 + nh0);
      rw3[mi] = *(const v4f*)(W3 + nh0);
    }

    for (int k = 0; k <= Tb + 2; ++k) {
      __syncthreads();
      const int pb = k & 1;
      const int tg = bid + k * S;
      const int t2 = tg - 2 * S;
      if (t2 >= 0 && t2 < ntiles) {
        const short* hbr = &ldsH[pb * HBUF];
        float* pPw = &ldsP[pb * PBUF];
#pragma unroll 1
        for (int nh = 0; nh < 2; ++nh) {
          v4f acc2[4][2];
#pragma unroll
          for (int mi = 0; mi < 4; ++mi) { acc2[mi][0] = rb2[mi]; acc2[mi][1] = rb2[mi]; }
          __builtin_amdgcn_s_setprio(1);
#pragma unroll
          for (int kt = 0; kt < 8; ++kt) {
            v8s bf0 = *(const v8s*)&hbr[((nh * 2 + 0) * 16 + lp) * LDH_S + kt * 32 + quad * 8];
            v8s bf1 = *(const v8s*)&hbr[((nh * 2 + 1) * 16 + lp) * LDH_S + kt * 32 + quad * 8];
#pragma unroll
            for (int mi = 0; mi < 4; ++mi) {
              acc2[mi][0] = __builtin_amdgcn_mfma_f32_16x16x32_bf16(rW2[mi][kt], bf0, acc2[mi][0], 0, 0, 0);
              acc2[mi][1] = __builtin_amdgcn_mfma_f32_16x16x32_bf16(rW2[mi][kt], bf1, acc2[mi][1], 0, 0, 0);
            }
          }
          __builtin_amdgcn_s_setprio(0);
          float s0 = 0.f, s1 = 0.f;
#pragma unroll
          for (int mi = 0; mi < 4; ++mi) {
#pragma unroll
            for (int r = 0; r < 4; ++r) {
              s0 += fmaxf(acc2[mi][0][r], 0.f) * rw3[mi][r];
              s1 += fmaxf(acc2[mi][1][r], 0.f) * rw3[mi][r];
            }
          }
          int e0 = (nh * 2 + 0) * 16 + lp, e1 = (nh * 2 + 1) * 16 + lp;
          pPw[e0 * LDP_S + wg * 4 + quad] = s0;
          pPw[e1 * LDP_S + wg * 4 + quad] = s1;
        }
      }
    }
  }
}

extern "C" void kernel_launch(void* const* d_in, const int* in_sizes, int n_in,
                              void* d_out, int out_size, void* d_ws, size_t ws_size,
                              hipStream_t stream) {
  const float* xu  = (const float*)d_in[0];
  const float* xm  = (const float*)d_in[1];
  const void*  ei  = d_in[2];
  const float* W1  = (const float*)d_in[3];
  const float* b1  = (const float*)d_in[4];
  const float* W2  = (const float*)d_in[5];
  const float* b2  = (const float*)d_in[6];
  const float* W3  = (const float*)d_in[7];
  const float* b3  = (const float*)d_in[8];
  float* out = (float*)d_out;

  const int E  = in_sizes[2] / 2;
  const int Nu = in_sizes[0] / 64;
  const int Nm = in_sizes[1] / 64;

  short* pW1 = (short*)d_ws;          // 64 KB
  short* pW2 = pW1 + 32768;           // 128 KB

  const int ntiles = (E + 63) / 64;
  const int nblk = ntiles < 256 ? ntiles : 256;

  const size_t need = 196608 + (size_t)(Nu + Nm) * 64 * 2;  // + bf16 tables

  if (ws_size >= need && Nu > 0 && Nm > 0) {
    short* xub = (short*)((char*)d_ws + 196608);
    short* xmb = xub + (size_t)Nu * 64;
    const int cvt_blocks = ((Nu + Nm) * 8 + 255) / 256;
    hipLaunchKernelGGL(prep, dim3(384 + cvt_blocks), dim3(256), 0, stream,
                       W1, W2, xu, xm, pW1, pW2, xub, xmb, Nu, Nm);

    hipFuncSetAttribute((const void*)mlp_v12,
                        hipFuncAttributeMaxDynamicSharedMemorySize, SMEM_BYTES);
    hipLaunchKernelGGL(mlp_v12, dim3(nblk), dim3(512), SMEM_BYTES, stream,
                       xub, xmb, ei, pW1, pW2, b1, b2, W3, b3, out, E);
  } else {
    hipLaunchKernelGGL(prep, dim3(384), dim3(256), 0, stream,
                       W1, W2, xu, xm, pW1, pW2, (short*)nullptr, (short*)nullptr, 0, 0);
    hipFuncSetAttribute((const void*)mlp_v9,
                        hipFuncAttributeMaxDynamicSharedMemorySize, SMEM_BYTES);
    hipLaunchKernelGGL(mlp_v9, dim3(nblk), dim3(512), SMEM_BYTES, stream,
                       xu, xm, ei, pW1, pW2, b1, b2, W3, b3, out, E);
  }
}